// Round 14
// baseline (2712.277 us; speedup 1.0000x reference)
//
#include <hip/hip_runtime.h>
#include <math.h>

#define HDIM 128
#define NSTEP 606
#define DSTR 129                 // dpl row stride (floats)
#define PXS 52                   // per-pixel activation stride (floats)
#define AW (4 * PXS)             // 208 floats per wave per buffer

#define O_T0 0
#define O_TA (8 * AW)
#define DYN_FLOATS (16 * AW)
#define DYN_BYTES (DYN_FLOATS * 4)   // 13312 B

// wpack float4 indices
#define WP_L5 2304
#define WP_L6 2688
#define WP_F4 2816               // total float4 count (45 KB)

typedef float v2f __attribute__((ext_vector_type(2)));
typedef float v4f __attribute__((ext_vector_type(4)));

__device__ __forceinline__ void pk_fma(v2f& acc, v2f a, v2f b) {
  asm("v_pk_fma_f32 %0, %1, %2, %0" : "+v"(acc) : "v"(a), "v"(b));
}
__device__ __forceinline__ v2f vlo(v4f v) { return __builtin_shufflevector(v, v, 0, 1); }
__device__ __forceinline__ v2f vhi(v4f v) { return __builtin_shufflevector(v, v, 2, 3); }
__device__ __forceinline__ v2f f4lo(float4 v) { return v2f{v.x, v.y}; }
__device__ __forceinline__ v2f f4hi(float4 v) { return v2f{v.z, v.w}; }

template <int CTRL>
__device__ __forceinline__ float dpp_qp(float v) {
  return __int_as_float(__builtin_amdgcn_mov_dpp(__float_as_int(v), CTRL, 0xf, 0xf, true));
}
// quad transpose-reduce: lane kq ends with full sum of px kq (verified R12/R13)
__device__ __forceinline__ float red4f(float a0, float a1, float a2, float a3,
                                       bool k1, bool k2) {
  float m0 = k1 ? a1 : a0, o0 = k1 ? a0 : a1;
  float m1 = k1 ? a3 : a2, o1 = k1 ? a2 : a3;
  m0 += dpp_qp<0xB1>(o0);
  m1 += dpp_qp<0xB1>(o1);
  float m = k2 ? m1 : m0, o = k2 ? m0 : m1;
  return m + dpp_qp<0x4E>(o);
}

template <bool RES>
__device__ __forceinline__ void compute48(const float4 (&w)[9],
    const float* __restrict__ src, float* __restrict__ dst,
    const float* __restrict__ res,
    float b0, float b1, float b2, int lt, int kq, bool k1, bool k2)
{
  float acc[3][4];
  #pragma unroll
  for (int px = 0; px < 4; ++px) {
    const float* sp = src + px * PXS + 12 * kq;
    const v4f t0v = *(const v4f*)sp;
    const v4f t1v = *(const v4f*)(sp + 4);
    const v4f t2v = *(const v4f*)(sp + 8);
    #pragma unroll
    for (int rr = 0; rr < 3; ++rr) {
      v2f a = {0.f, 0.f};
      pk_fma(a, f4lo(w[rr * 3 + 0]), vlo(t0v)); pk_fma(a, f4hi(w[rr * 3 + 0]), vhi(t0v));
      pk_fma(a, f4lo(w[rr * 3 + 1]), vlo(t1v)); pk_fma(a, f4hi(w[rr * 3 + 1]), vhi(t1v));
      pk_fma(a, f4lo(w[rr * 3 + 2]), vlo(t2v)); pk_fma(a, f4hi(w[rr * 3 + 2]), vhi(t2v));
      acc[rr][px] = a.x + a.y;
    }
  }
  {
    float z = red4f(acc[0][0], acc[0][1], acc[0][2], acc[0][3], k1, k2) + b0;
    z = fmaxf(z, 0.01f * z);
    if (RES) z += res[kq * PXS + lt];
    dst[kq * PXS + lt] = z;
  }
  {
    float z = red4f(acc[1][0], acc[1][1], acc[1][2], acc[1][3], k1, k2) + b1;
    z = fmaxf(z, 0.01f * z);
    if (RES) z += res[kq * PXS + lt + 16];
    dst[kq * PXS + lt + 16] = z;
  }
  {
    float z = red4f(acc[2][0], acc[2][1], acc[2][2], acc[2][3], k1, k2) + b2;
    z = fmaxf(z, 0.01f * z);
    if (RES) z += res[kq * PXS + lt + 32];
    dst[kq * PXS + lt + 32] = z;
  }
}

__global__ __launch_bounds__(512)
void codec_main_kernel(const float* __restrict__ x,
    const float* __restrict__ b1, const float* __restrict__ b2,
    const float* __restrict__ b3, const float* __restrict__ b4,
    const float* __restrict__ b5, const float* __restrict__ b6,
    const float* __restrict__ W7, const float* __restrict__ b7,
    const float4* __restrict__ wp4,
    unsigned* __restrict__ g_hist, float* __restrict__ g_sumsq)
{
  __shared__ float s_dpl[122 * DSTR];      // 62952 B
  __shared__ unsigned s_hist[256];
  __shared__ float s_wred[8];
  extern __shared__ float dyn[];

  const int tid = threadIdx.x, wid = tid >> 6, lane = tid & 63;
  const int plane = blockIdx.x;
  const float* xp = x + (size_t)plane * (HDIM * HDIM);
  float* t0b = dyn + O_T0 + wid * AW;      // [4 px][PXS]
  float* tab = dyn + O_TA + wid * AW;

  for (int i = tid; i < 122 * DSTR; i += 512) s_dpl[i] = 0.f;
  for (int i = tid; i < DYN_FLOATS; i += 512) dyn[i] = 0.f;
  if (tid < 256) s_hist[tid] = 0u;
  if (tid < 8) s_wred[tid] = 0.f;

  // ---- per-lane constants ----
  const int lt = lane >> 2, kq = lane & 3;
  const bool k1 = kq & 1, k2 = kq & 2;
  const int lt12 = lt % 12;
  float b14[4][3];
  {
    const float* Bs[4] = {b1, b2, b3, b4};
    #pragma unroll
    for (int L = 0; L < 4; ++L)
      #pragma unroll
      for (int rr = 0; rr < 3; ++rr) b14[L][rr] = Bs[L][lt + 16 * rr];
  }
  const float b5a = b5[lt12], b5b = b5[lt12 + 12];
  const float b6v = b6[lt12];
  const float w7r = (lt < 12) ? W7[lt] : 0.f;
  const float B7v = b7[0];

  // ---- gather geometry ----
  const bool isx = (lane < 24);
  const bool isd = (lane >= 24 && lane < 48);
  int xro = 0, xco = 0, dro = 0, dco = 0;
  if (isx) { xro = (lane < 21) ? lane / 7 : 3; xco = (lane < 21) ? lane % 7 : (lane - 21); }
  if (isd) { const int g = lane - 24; dro = (g < 21) ? g / 7 - 3 : 0; dco = (g < 21) ? g % 7 : g - 21; }

  __syncthreads();

  float xpre[4] = {0.f, 0.f, 0.f, 0.f};
  float xcp = 0.f;
  float sumsq = 0.f;
  {
    const int rb0 = wid & 7;
    #pragma unroll
    for (int u = 0; u < 4; ++u) {
      const int r = rb0 + 8 * u, j = 0 - 4 * r;
      if (isx && j >= 0 && r <= 121) xpre[u] = xp[(r + xro) * HDIM + (j + xco)];
    }
    if (lane < 4 && (rb0 + 8 * lane) == 0) xcp = xp[3 * HDIM + 3];
  }

  // ---- prime the cross-step pipeline: wA = L1 weights, wB = L2 weights ----
  float4 wA[9], wB[9];
  #pragma unroll
  for (int j = 0; j < 9; ++j) wA[j] = wp4[j * 64 + lane];
  #pragma unroll
  for (int j = 0; j < 9; ++j) wB[j] = wp4[(9 + j) * 64 + lane];

  for (int T = 0; T < NSTEP; ++T) {
    const int r_lo = (T > 121) ? ((T - 118) >> 2) : 0;
    const int rbase = r_lo + ((wid - r_lo) & 7);
    const bool active = (4 * rbase <= T) && (rbase <= 121);

    // ---- gather t0 [px][f] ----
    if (active && lane < 48) {
      #pragma unroll
      for (int u = 0; u < 4; ++u) {
        const int r = rbase + 8 * u, j = T - 4 * r;
        float v = 0.f;
        if (j >= 0 && r <= 121) {
          if (isx) v = xpre[u];
          else {
            const int drow = r + dro, dcol = j + dco;
            v = (drow >= 0) ? s_dpl[drow * DSTR + dcol] : 0.f;
          }
        }
        t0b[u * PXS + lane] = v;
      }
    }

    // ---- unconditional x prefetch for T+1 ----
    float xcn = 0.f;
    {
      const int Tn = T + 1;
      const int r_lo_n = (Tn > 121) ? ((Tn - 118) >> 2) : 0;
      const int rbase_n = r_lo_n + ((wid - r_lo_n) & 7);
      #pragma unroll
      for (int u = 0; u < 4; ++u) {
        const int rn = rbase_n + 8 * u, jn = Tn - 4 * rn;
        if (isx && jn >= 0 && rn <= 121) xpre[u] = xp[(rn + xro) * HDIM + (jn + xco)];
      }
      if (lane < 4) {
        const int rn = rbase_n + 8 * lane, jn = Tn - 4 * rn;
        if (jn >= 0 && rn <= 121) xcn = xp[(rn + 3) * HDIM + (jn + 3)];
      }
    }

    if (active) {
      float4 wC[9];                         // L3/L5 staging
      // L1: wA ready from previous step; issue L3 into wC
      #pragma unroll
      for (int j = 0; j < 9; ++j) wC[j] = wp4[(18 + j) * 64 + lane];
      compute48<false>(wA, t0b, tab, t0b, b14[0][0], b14[0][1], b14[0][2], lt, kq, k1, k2);
      // L2: wB ready; issue L4 into wA (free after L1)
      #pragma unroll
      for (int j = 0; j < 9; ++j) wA[j] = wp4[(27 + j) * 64 + lane];
      compute48<false>(wB, tab, tab, t0b, b14[1][0], b14[1][1], b14[1][2], lt, kq, k1, k2);
      // L3: wC; issue L5 + L6 into wB (free after L2)
      #pragma unroll
      for (int j = 0; j < 6; ++j) wB[j] = wp4[WP_L5 + j * 64 + lane];
      float4 w6a = wp4[WP_L6 + lane];
      float4 w6b = wp4[WP_L6 + 64 + lane];
      compute48<false>(wC, tab, tab, t0b, b14[2][0], b14[2][1], b14[2][2], lt, kq, k1, k2);
      // L4: wA; after it, wA is free -> reload L1 for NEXT step
      compute48<true>(wA, tab, tab, t0b, b14[3][0], b14[3][1], b14[3][2], lt, kq, k1, k2);
      #pragma unroll
      for (int j = 0; j < 9; ++j) wA[j] = wp4[j * 64 + lane];

      // ---- L5: 48->24 (rows lt12, lt12+12), tab -> t0b, weights wB[0..5] ----
      {
        float acc0[4], acc1[4];
        #pragma unroll
        for (int px = 0; px < 4; ++px) {
          const float* sp = tab + px * PXS + 12 * kq;
          const v4f t0v = *(const v4f*)sp;
          const v4f t1v = *(const v4f*)(sp + 4);
          const v4f t2v = *(const v4f*)(sp + 8);
          v2f a0 = {0.f, 0.f}, a1 = {0.f, 0.f};
          pk_fma(a0, f4lo(wB[0]), vlo(t0v)); pk_fma(a0, f4hi(wB[0]), vhi(t0v));
          pk_fma(a0, f4lo(wB[1]), vlo(t1v)); pk_fma(a0, f4hi(wB[1]), vhi(t1v));
          pk_fma(a0, f4lo(wB[2]), vlo(t2v)); pk_fma(a0, f4hi(wB[2]), vhi(t2v));
          pk_fma(a1, f4lo(wB[3]), vlo(t0v)); pk_fma(a1, f4hi(wB[3]), vhi(t0v));
          pk_fma(a1, f4lo(wB[4]), vlo(t1v)); pk_fma(a1, f4hi(wB[4]), vhi(t1v));
          pk_fma(a1, f4lo(wB[5]), vlo(t2v)); pk_fma(a1, f4hi(wB[5]), vhi(t2v));
          acc0[px] = a0.x + a0.y; acc1[px] = a1.x + a1.y;
        }
        float za = red4f(acc0[0], acc0[1], acc0[2], acc0[3], k1, k2) + b5a;
        float zb = red4f(acc1[0], acc1[1], acc1[2], acc1[3], k1, k2) + b5b;
        za = fmaxf(za, 0.01f * za);
        zb = fmaxf(zb, 0.01f * zb);
        if (lt < 12) {
          t0b[kq * PXS + lt12] = za;
          t0b[kq * PXS + lt12 + 12] = zb;
        }
      }
      // wB free -> reload L2 for NEXT step (hides under L6/L7/barrier/gather)
      #pragma unroll
      for (int j = 0; j < 9; ++j) wB[j] = wp4[(9 + j) * 64 + lane];

      // ---- L6 (row lt12) + L7 + delta ----
      {
        float acc[4];
        #pragma unroll
        for (int px = 0; px < 4; ++px) {
          const float* sp = t0b + px * PXS + 6 * kq;
          const v2f d0 = *(const v2f*)sp;
          const v2f d1 = *(const v2f*)(sp + 2);
          const v2f d2 = *(const v2f*)(sp + 4);
          v2f a = {0.f, 0.f};
          pk_fma(a, f4lo(w6a), d0);
          pk_fma(a, f4hi(w6a), d1);
          pk_fma(a, v2f{w6b.x, w6b.y}, d2);
          acc[px] = a.x + a.y;
        }
        float h6 = red4f(acc[0], acc[1], acc[2], acc[3], k1, k2) + b6v;
        h6 = fmaxf(h6, 0.01f * h6);
        float s = w7r * h6;                 // 0 for lt>=12
        s += __shfl_xor(s, 4);
        s += __shfl_xor(s, 8);
        s += __shfl_xor(s, 16);
        s += __shfl_xor(s, 32);

        if (lane < 4) {
          const int r = rbase + 8 * lane, j = T - 4 * r;
          if (j >= 0 && r <= 121) {
            const float pred = fminf(1.f, fmaxf(-1.f, s + B7v));
            const float delta = xcp - pred;
            s_dpl[r * DSTR + j + 3] = delta;
            sumsq += delta * delta;
            if (delta <= 1.0f) {
              int bin = (int)((delta + 1.0f) * 128.0f);
              bin = bin > 255 ? 255 : (bin < 0 ? 0 : bin);
              atomicAdd(&s_hist[bin], 1u);
            }
          }
        }
      }
    }
    xcp = xcn;
    __syncthreads();
  }

  // ---- stats flush ----
  {
    float v = sumsq;
    #pragma unroll
    for (int off = 32; off; off >>= 1) v += __shfl_down(v, off);
    if (lane == 0) s_wred[wid] = v;
  }
  __syncthreads();
  if (tid == 0) {
    float s = 0.f;
    #pragma unroll
    for (int w = 0; w < 8; ++w) s += s_wred[w];
    g_sumsq[plane] = s;
  }
  if (tid < 256) {
    const unsigned c = s_hist[tid];
    if (c) atomicAdd(&g_hist[tid], c);
  }
}

// init + pack: per-lane float4 weight chunks, coalesced layout [chunk][lane]
__global__ void codec_init_kernel(const float* __restrict__ W1, const float* __restrict__ W2,
                                  const float* __restrict__ W3, const float* __restrict__ W4,
                                  const float* __restrict__ W5, const float* __restrict__ W6,
                                  unsigned* __restrict__ g_hist, float* __restrict__ g_sumsq,
                                  float* __restrict__ wpack)
{
  const int gid = blockIdx.x * 256 + threadIdx.x;
  if (gid < 256) g_hist[gid] = 0u;
  if (gid < 24) g_sumsq[gid] = 0.f;
  if (gid < WP_F4 * 4) {
    const int f4 = gid >> 2, e = gid & 3;
    float val;
    if (f4 < WP_L5) {
      const int L = f4 / 576, rem = f4 % 576, j = rem >> 6, ln = rem & 63;
      const int lt = ln >> 2, kq = ln & 3, rr = j / 3, ic = j % 3;
      const float* W = (L == 0) ? W1 : (L == 1) ? W2 : (L == 2) ? W3 : W4;
      val = W[(lt + 16 * rr) * 48 + 12 * kq + 4 * ic + e];
    } else if (f4 < WP_L6) {
      const int t = f4 - WP_L5, j = t >> 6, ln = t & 63;
      const int lt12 = (ln >> 2) % 12, kq = ln & 3, r01 = j / 3, ic = j % 3;
      val = W5[(lt12 + 12 * r01) * 48 + 12 * kq + 4 * ic + e];
    } else {
      const int t = f4 - WP_L6, j = t >> 6, ln = t & 63;
      const int lt12 = (ln >> 2) % 12, kq = ln & 3, k = j * 4 + e;
      val = (k < 6) ? W6[lt12 * 24 + 6 * kq + k] : 0.f;
    }
    wpack[gid] = val;
  }
}

__global__ void codec_final_kernel(const unsigned* __restrict__ g_hist,
                                   const float* __restrict__ g_sumsq,
                                   float* __restrict__ out)
{
  __shared__ float sred[256];
  const int t = threadIdx.x;
  sred[t] = (t < 24) ? g_sumsq[t] : 0.f;
  __syncthreads();
  for (int off = 128; off; off >>= 1) {
    if (t < off) sred[t] += sred[t + off];
    __syncthreads();
  }
  const float loss = sqrtf(sred[0] / 387072.f);   // 8*3*126*128
  __syncthreads();

  const unsigned c = g_hist[t] + (t == 128 ? 2928u : 0u);  // bottom zero-row
  float ent = 0.f;
  if (c) {
    const float pr = (float)c / 360144.0f;        // 24*123*122
    ent = -pr * log2f(pr);
  }
  sred[t] = ent;
  __syncthreads();
  for (int off = 128; off; off >>= 1) {
    if (t < off) sred[t] += sred[t + off];
    __syncthreads();
  }
  if (t == 0) { out[0] = loss; out[1] = sred[0] * 0.125f; }
}

extern "C" void kernel_launch(void* const* d_in, const int* in_sizes, int n_in,
                              void* d_out, int out_size, void* d_ws, size_t ws_size,
                              hipStream_t stream) {
  const float* x  = (const float*)d_in[0];
  const float* W1 = (const float*)d_in[1];  const float* b1 = (const float*)d_in[2];
  const float* W2 = (const float*)d_in[3];  const float* b2 = (const float*)d_in[4];
  const float* W3 = (const float*)d_in[5];  const float* b3 = (const float*)d_in[6];
  const float* W4 = (const float*)d_in[7];  const float* b4 = (const float*)d_in[8];
  const float* W5 = (const float*)d_in[9];  const float* b5 = (const float*)d_in[10];
  const float* W6 = (const float*)d_in[11]; const float* b6 = (const float*)d_in[12];
  const float* W7 = (const float*)d_in[13]; const float* b7 = (const float*)d_in[14];

  unsigned* g_hist = (unsigned*)d_ws;              // 256 u32
  float* g_sumsq = (float*)d_ws + 256;             // 24 f32
  float* wpack   = (float*)d_ws + 512;             // 11264 f32 (45 KB), 16B-aligned

  codec_init_kernel<<<44, 256, 0, stream>>>(W1, W2, W3, W4, W5, W6,
                                            g_hist, g_sumsq, wpack);
  codec_main_kernel<<<24, 512, DYN_BYTES, stream>>>(x, b1, b2, b3, b4, b5, b6, W7, b7,
                                                    (const float4*)wpack,
                                                    g_hist, g_sumsq);
  codec_final_kernel<<<1, 256, 0, stream>>>(g_hist, g_sumsq, (float*)d_out);
}

// Round 15
// 2633.114 us; speedup vs baseline: 1.0301x; 1.0301x over previous
//
#include <hip/hip_runtime.h>
#include <math.h>

#define HDIM 128
#define NSTEP 606
#define DSTR 129                 // dpl row stride (floats)
#define PXS 52                   // per-pixel activation stride (floats)
#define AW (4 * PXS)             // 208 floats per wave per buffer

#define O_T0 0
#define O_TA (8 * AW)
#define DYN_FLOATS (16 * AW)
#define DYN_BYTES (DYN_FLOATS * 4)   // 13312 B

// wpack float4 indices
#define WP_L5 2304
#define WP_L6 2688
#define WP_F4 2816               // total float4 count (45 KB)

typedef float v2f __attribute__((ext_vector_type(2)));
typedef float v4f __attribute__((ext_vector_type(4)));

__device__ __forceinline__ void pk_fma(v2f& acc, v2f a, v2f b) {
  asm("v_pk_fma_f32 %0, %1, %2, %0" : "+v"(acc) : "v"(a), "v"(b));
}
__device__ __forceinline__ v2f vlo(v4f v) { return __builtin_shufflevector(v, v, 0, 1); }
__device__ __forceinline__ v2f vhi(v4f v) { return __builtin_shufflevector(v, v, 2, 3); }
__device__ __forceinline__ v2f f4lo(float4 v) { return v2f{v.x, v.y}; }
__device__ __forceinline__ v2f f4hi(float4 v) { return v2f{v.z, v.w}; }

template <int CTRL>
__device__ __forceinline__ float dpp_qp(float v) {
  return __int_as_float(__builtin_amdgcn_mov_dpp(__float_as_int(v), CTRL, 0xf, 0xf, true));
}
// quad transpose-reduce: lane kq ends with full sum of px kq (verified R12/R13)
__device__ __forceinline__ float red4f(float a0, float a1, float a2, float a3,
                                       bool k1, bool k2) {
  float m0 = k1 ? a1 : a0, o0 = k1 ? a0 : a1;
  float m1 = k1 ? a3 : a2, o1 = k1 ? a2 : a3;
  m0 += dpp_qp<0xB1>(o0);
  m1 += dpp_qp<0xB1>(o1);
  float m = k2 ? m1 : m0, o = k2 ? m0 : m1;
  return m + dpp_qp<0x4E>(o);
}

// barrier that drains only LDS (lgkmcnt), leaving global loads in flight
__device__ __forceinline__ void lds_barrier() {
  asm volatile("s_waitcnt lgkmcnt(0)" ::: "memory");
  __builtin_amdgcn_s_barrier();
  asm volatile("" ::: "memory");
}

template <bool RES>
__device__ __forceinline__ void compute48(const float4 (&w)[9],
    const float* __restrict__ src, float* __restrict__ dst,
    const float* __restrict__ res,
    float b0, float b1, float b2, int lt, int kq, bool k1, bool k2)
{
  float acc[3][4];
  #pragma unroll
  for (int px = 0; px < 4; ++px) {
    const float* sp = src + px * PXS + 12 * kq;
    const v4f t0v = *(const v4f*)sp;
    const v4f t1v = *(const v4f*)(sp + 4);
    const v4f t2v = *(const v4f*)(sp + 8);
    #pragma unroll
    for (int rr = 0; rr < 3; ++rr) {
      v2f a = {0.f, 0.f};
      pk_fma(a, f4lo(w[rr * 3 + 0]), vlo(t0v)); pk_fma(a, f4hi(w[rr * 3 + 0]), vhi(t0v));
      pk_fma(a, f4lo(w[rr * 3 + 1]), vlo(t1v)); pk_fma(a, f4hi(w[rr * 3 + 1]), vhi(t1v));
      pk_fma(a, f4lo(w[rr * 3 + 2]), vlo(t2v)); pk_fma(a, f4hi(w[rr * 3 + 2]), vhi(t2v));
      acc[rr][px] = a.x + a.y;
    }
  }
  {
    float z = red4f(acc[0][0], acc[0][1], acc[0][2], acc[0][3], k1, k2) + b0;
    z = fmaxf(z, 0.01f * z);
    if (RES) z += res[kq * PXS + lt];
    dst[kq * PXS + lt] = z;
  }
  {
    float z = red4f(acc[1][0], acc[1][1], acc[1][2], acc[1][3], k1, k2) + b1;
    z = fmaxf(z, 0.01f * z);
    if (RES) z += res[kq * PXS + lt + 16];
    dst[kq * PXS + lt + 16] = z;
  }
  {
    float z = red4f(acc[2][0], acc[2][1], acc[2][2], acc[2][3], k1, k2) + b2;
    z = fmaxf(z, 0.01f * z);
    if (RES) z += res[kq * PXS + lt + 32];
    dst[kq * PXS + lt + 32] = z;
  }
}

__global__ __launch_bounds__(512)
void codec_main_kernel(const float* __restrict__ x,
    const float* __restrict__ b1, const float* __restrict__ b2,
    const float* __restrict__ b3, const float* __restrict__ b4,
    const float* __restrict__ b5, const float* __restrict__ b6,
    const float* __restrict__ W7, const float* __restrict__ b7,
    const float4* __restrict__ wp4,
    unsigned* __restrict__ g_hist, float* __restrict__ g_sumsq)
{
  __shared__ float s_dpl[122 * DSTR];      // 62952 B
  __shared__ unsigned s_hist[256];
  __shared__ float s_wred[8];
  extern __shared__ float dyn[];

  const int tid = threadIdx.x, wid = tid >> 6, lane = tid & 63;
  const int plane = blockIdx.x;
  const float* xp = x + (size_t)plane * (HDIM * HDIM);
  float* t0b = dyn + O_T0 + wid * AW;      // [4 px][PXS]
  float* tab = dyn + O_TA + wid * AW;

  for (int i = tid; i < 122 * DSTR; i += 512) s_dpl[i] = 0.f;
  for (int i = tid; i < DYN_FLOATS; i += 512) dyn[i] = 0.f;
  if (tid < 256) s_hist[tid] = 0u;
  if (tid < 8) s_wred[tid] = 0.f;

  // ---- per-lane constants ----
  const int lt = lane >> 2, kq = lane & 3;
  const bool k1 = kq & 1, k2 = kq & 2;
  const int lt12 = lt % 12;
  float b14[4][3];
  {
    const float* Bs[4] = {b1, b2, b3, b4};
    #pragma unroll
    for (int L = 0; L < 4; ++L)
      #pragma unroll
      for (int rr = 0; rr < 3; ++rr) b14[L][rr] = Bs[L][lt + 16 * rr];
  }
  const float b5a = b5[lt12], b5b = b5[lt12 + 12];
  const float b6v = b6[lt12];
  const float w7r = (lt < 12) ? W7[lt] : 0.f;
  const float B7v = b7[0];
  // loop-invariant L6 weights: hoisted (were reloaded every step)
  const float4 w6a = wp4[WP_L6 + lane];
  const float4 w6b = wp4[WP_L6 + 64 + lane];

  // ---- gather geometry ----
  const bool isx = (lane < 24);
  const bool isd = (lane >= 24 && lane < 48);
  int xro = 0, xco = 0, dro = 0, dco = 0;
  if (isx) { xro = (lane < 21) ? lane / 7 : 3; xco = (lane < 21) ? lane % 7 : (lane - 21); }
  if (isd) { const int g = lane - 24; dro = (g < 21) ? g / 7 - 3 : 0; dco = (g < 21) ? g % 7 : g - 21; }

  __syncthreads();

  float xpre[4] = {0.f, 0.f, 0.f, 0.f};
  float xcp = 0.f;
  float sumsq = 0.f;
  {
    const int rb0 = wid & 7;
    #pragma unroll
    for (int u = 0; u < 4; ++u) {
      const int r = rb0 + 8 * u, j = 0 - 4 * r;
      if (isx && j >= 0 && r <= 121) xpre[u] = xp[(r + xro) * HDIM + (j + xco)];
    }
    if (lane < 4 && (rb0 + 8 * lane) == 0) xcp = xp[3 * HDIM + 3];
  }

  for (int T = 0; T < NSTEP; ++T) {
    const int r_lo = (T > 121) ? ((T - 118) >> 2) : 0;
    const int rbase = r_lo + ((wid - r_lo) & 7);
    const bool active = (4 * rbase <= T) && (rbase <= 121);

    // ---- gather t0 [px][f] ----
    if (active && lane < 48) {
      #pragma unroll
      for (int u = 0; u < 4; ++u) {
        const int r = rbase + 8 * u, j = T - 4 * r;
        float v = 0.f;
        if (j >= 0 && r <= 121) {
          if (isx) v = xpre[u];
          else {
            const int drow = r + dro, dcol = j + dco;
            v = (drow >= 0) ? s_dpl[drow * DSTR + dcol] : 0.f;
          }
        }
        t0b[u * PXS + lane] = v;
      }
    }

    // ---- unconditional x prefetch for T+1 (stays in flight across barrier) ----
    float xcn = 0.f;
    {
      const int Tn = T + 1;
      const int r_lo_n = (Tn > 121) ? ((Tn - 118) >> 2) : 0;
      const int rbase_n = r_lo_n + ((wid - r_lo_n) & 7);
      #pragma unroll
      for (int u = 0; u < 4; ++u) {
        const int rn = rbase_n + 8 * u, jn = Tn - 4 * rn;
        if (isx && jn >= 0 && rn <= 121) xpre[u] = xp[(rn + xro) * HDIM + (jn + xco)];
      }
      if (lane < 4) {
        const int rn = rbase_n + 8 * lane, jn = Tn - 4 * rn;
        if (jn >= 0 && rn <= 121) xcn = xp[(rn + 3) * HDIM + (jn + 3)];
      }
    }

    if (active) {
      __builtin_amdgcn_s_setprio(1);
      float4 wA[9], wB[9];
      #pragma unroll
      for (int j = 0; j < 9; ++j) wA[j] = wp4[j * 64 + lane];
      #pragma unroll
      for (int j = 0; j < 9; ++j) wB[j] = wp4[(9 + j) * 64 + lane];
      compute48<false>(wA, t0b, tab, t0b, b14[0][0], b14[0][1], b14[0][2], lt, kq, k1, k2);
      #pragma unroll
      for (int j = 0; j < 9; ++j) wA[j] = wp4[(18 + j) * 64 + lane];
      compute48<false>(wB, tab, tab, t0b, b14[1][0], b14[1][1], b14[1][2], lt, kq, k1, k2);
      #pragma unroll
      for (int j = 0; j < 9; ++j) wB[j] = wp4[(27 + j) * 64 + lane];
      compute48<false>(wA, tab, tab, t0b, b14[2][0], b14[2][1], b14[2][2], lt, kq, k1, k2);
      #pragma unroll
      for (int j = 0; j < 6; ++j) wA[j] = wp4[WP_L5 + j * 64 + lane];
      compute48<true>(wB, tab, tab, t0b, b14[3][0], b14[3][1], b14[3][2], lt, kq, k1, k2);

      // ---- L5: 48->24 (rows lt12, lt12+12), tab -> t0b ----
      {
        float acc0[4], acc1[4];
        #pragma unroll
        for (int px = 0; px < 4; ++px) {
          const float* sp = tab + px * PXS + 12 * kq;
          const v4f t0v = *(const v4f*)sp;
          const v4f t1v = *(const v4f*)(sp + 4);
          const v4f t2v = *(const v4f*)(sp + 8);
          v2f a0 = {0.f, 0.f}, a1 = {0.f, 0.f};
          pk_fma(a0, f4lo(wA[0]), vlo(t0v)); pk_fma(a0, f4hi(wA[0]), vhi(t0v));
          pk_fma(a0, f4lo(wA[1]), vlo(t1v)); pk_fma(a0, f4hi(wA[1]), vhi(t1v));
          pk_fma(a0, f4lo(wA[2]), vlo(t2v)); pk_fma(a0, f4hi(wA[2]), vhi(t2v));
          pk_fma(a1, f4lo(wA[3]), vlo(t0v)); pk_fma(a1, f4hi(wA[3]), vhi(t0v));
          pk_fma(a1, f4lo(wA[4]), vlo(t1v)); pk_fma(a1, f4hi(wA[4]), vhi(t1v));
          pk_fma(a1, f4lo(wA[5]), vlo(t2v)); pk_fma(a1, f4hi(wA[5]), vhi(t2v));
          acc0[px] = a0.x + a0.y; acc1[px] = a1.x + a1.y;
        }
        float za = red4f(acc0[0], acc0[1], acc0[2], acc0[3], k1, k2) + b5a;
        float zb = red4f(acc1[0], acc1[1], acc1[2], acc1[3], k1, k2) + b5b;
        za = fmaxf(za, 0.01f * za);
        zb = fmaxf(zb, 0.01f * zb);
        if (lt < 12) {
          t0b[kq * PXS + lt12] = za;
          t0b[kq * PXS + lt12 + 12] = zb;
        }
      }

      // ---- L6 (row lt12) + L7 + delta ----
      {
        float acc[4];
        #pragma unroll
        for (int px = 0; px < 4; ++px) {
          const float* sp = t0b + px * PXS + 6 * kq;
          const v2f d0 = *(const v2f*)sp;
          const v2f d1 = *(const v2f*)(sp + 2);
          const v2f d2 = *(const v2f*)(sp + 4);
          v2f a = {0.f, 0.f};
          pk_fma(a, f4lo(w6a), d0);
          pk_fma(a, f4hi(w6a), d1);
          pk_fma(a, v2f{w6b.x, w6b.y}, d2);
          acc[px] = a.x + a.y;
        }
        float h6 = red4f(acc[0], acc[1], acc[2], acc[3], k1, k2) + b6v;
        h6 = fmaxf(h6, 0.01f * h6);
        float s = w7r * h6;                 // 0 for lt>=12
        s += __shfl_xor(s, 4);
        s += __shfl_xor(s, 8);
        s += __shfl_xor(s, 16);
        s += __shfl_xor(s, 32);

        if (lane < 4) {
          const int r = rbase + 8 * lane, j = T - 4 * r;
          if (j >= 0 && r <= 121) {
            const float pred = fminf(1.f, fmaxf(-1.f, s + B7v));
            const float delta = xcp - pred;
            s_dpl[r * DSTR + j + 3] = delta;
            sumsq += delta * delta;
            if (delta <= 1.0f) {
              int bin = (int)((delta + 1.0f) * 128.0f);
              bin = bin > 255 ? 255 : (bin < 0 ? 0 : bin);
              atomicAdd(&s_hist[bin], 1u);
            }
          }
        }
      }
      __builtin_amdgcn_s_setprio(0);
    }
    xcp = xcn;
    // LDS-only barrier: delta writes ordered; global prefetches stay in flight
    lds_barrier();
  }

  // ---- stats flush ----
  {
    float v = sumsq;
    #pragma unroll
    for (int off = 32; off; off >>= 1) v += __shfl_down(v, off);
    if (lane == 0) s_wred[wid] = v;
  }
  __syncthreads();
  if (tid == 0) {
    float s = 0.f;
    #pragma unroll
    for (int w = 0; w < 8; ++w) s += s_wred[w];
    g_sumsq[plane] = s;
  }
  if (tid < 256) {
    const unsigned c = s_hist[tid];
    if (c) atomicAdd(&g_hist[tid], c);
  }
}

// init + pack: per-lane float4 weight chunks, coalesced layout [chunk][lane]
__global__ void codec_init_kernel(const float* __restrict__ W1, const float* __restrict__ W2,
                                  const float* __restrict__ W3, const float* __restrict__ W4,
                                  const float* __restrict__ W5, const float* __restrict__ W6,
                                  unsigned* __restrict__ g_hist, float* __restrict__ g_sumsq,
                                  float* __restrict__ wpack)
{
  const int gid = blockIdx.x * 256 + threadIdx.x;
  if (gid < 256) g_hist[gid] = 0u;
  if (gid < 24) g_sumsq[gid] = 0.f;
  if (gid < WP_F4 * 4) {
    const int f4 = gid >> 2, e = gid & 3;
    float val;
    if (f4 < WP_L5) {
      const int L = f4 / 576, rem = f4 % 576, j = rem >> 6, ln = rem & 63;
      const int lt = ln >> 2, kq = ln & 3, rr = j / 3, ic = j % 3;
      const float* W = (L == 0) ? W1 : (L == 1) ? W2 : (L == 2) ? W3 : W4;
      val = W[(lt + 16 * rr) * 48 + 12 * kq + 4 * ic + e];
    } else if (f4 < WP_L6) {
      const int t = f4 - WP_L5, j = t >> 6, ln = t & 63;
      const int lt12 = (ln >> 2) % 12, kq = ln & 3, r01 = j / 3, ic = j % 3;
      val = W5[(lt12 + 12 * r01) * 48 + 12 * kq + 4 * ic + e];
    } else {
      const int t = f4 - WP_L6, j = t >> 6, ln = t & 63;
      const int lt12 = (ln >> 2) % 12, kq = ln & 3, k = j * 4 + e;
      val = (k < 6) ? W6[lt12 * 24 + 6 * kq + k] : 0.f;
    }
    wpack[gid] = val;
  }
}

__global__ void codec_final_kernel(const unsigned* __restrict__ g_hist,
                                   const float* __restrict__ g_sumsq,
                                   float* __restrict__ out)
{
  __shared__ float sred[256];
  const int t = threadIdx.x;
  sred[t] = (t < 24) ? g_sumsq[t] : 0.f;
  __syncthreads();
  for (int off = 128; off; off >>= 1) {
    if (t < off) sred[t] += sred[t + off];
    __syncthreads();
  }
  const float loss = sqrtf(sred[0] / 387072.f);   // 8*3*126*128
  __syncthreads();

  const unsigned c = g_hist[t] + (t == 128 ? 2928u : 0u);  // bottom zero-row
  float ent = 0.f;
  if (c) {
    const float pr = (float)c / 360144.0f;        // 24*123*122
    ent = -pr * log2f(pr);
  }
  sred[t] = ent;
  __syncthreads();
  for (int off = 128; off; off >>= 1) {
    if (t < off) sred[t] += sred[t + off];
    __syncthreads();
  }
  if (t == 0) { out[0] = loss; out[1] = sred[0] * 0.125f; }
}

extern "C" void kernel_launch(void* const* d_in, const int* in_sizes, int n_in,
                              void* d_out, int out_size, void* d_ws, size_t ws_size,
                              hipStream_t stream) {
  const float* x  = (const float*)d_in[0];
  const float* W1 = (const float*)d_in[1];  const float* b1 = (const float*)d_in[2];
  const float* W2 = (const float*)d_in[3];  const float* b2 = (const float*)d_in[4];
  const float* W3 = (const float*)d_in[5];  const float* b3 = (const float*)d_in[6];
  const float* W4 = (const float*)d_in[7];  const float* b4 = (const float*)d_in[8];
  const float* W5 = (const float*)d_in[9];  const float* b5 = (const float*)d_in[10];
  const float* W6 = (const float*)d_in[11]; const float* b6 = (const float*)d_in[12];
  const float* W7 = (const float*)d_in[13]; const float* b7 = (const float*)d_in[14];

  unsigned* g_hist = (unsigned*)d_ws;              // 256 u32
  float* g_sumsq = (float*)d_ws + 256;             // 24 f32
  float* wpack   = (float*)d_ws + 512;             // 11264 f32 (45 KB), 16B-aligned

  codec_init_kernel<<<44, 256, 0, stream>>>(W1, W2, W3, W4, W5, W6,
                                            g_hist, g_sumsq, wpack);
  codec_main_kernel<<<24, 512, DYN_BYTES, stream>>>(x, b1, b2, b3, b4, b5, b6, W7, b7,
                                                    (const float4*)wpack,
                                                    g_hist, g_sumsq);
  codec_final_kernel<<<1, 256, 0, stream>>>(g_hist, g_sumsq, (float*)d_out);
}